// Round 6
// baseline (482.180 us; speedup 1.0000x reference)
//
#include <hip/hip_runtime.h>

// KCenterSampler FPS — LDS-resident coords + zero-barrier per-wave sync.
// 8 segments × 16 blocks (128 blocks, cooperative). Each 256-thread block
// owns 392 points; coords live in LDS as float2 channel-pairs (55 KB,
// thread-private access, conflict-free ds_read_b64). Per FPS step:
//   register distance update -> wave butterfly argmax (all lanes) ->
//   per-WAVE slot publish (RELAXED agent) -> 64-lane poll of the 64
//   per-step slots -> butterfly max -> winner in every lane.
// NO __syncthreads in the step loop; waves free-run (slots are per-step).
// Arithmetic bit-identical to the verified round-1/3/4 kernels (absmax 0).

#define NPTS 6272
#define CDIM 35
#define NPAIR 18                // ceil(35/2) channel pairs (last padded w/ 0)
#define BT   8
#define KSEL 128
#define THW  12544
#define BPS  16                 // blocks per segment
#define PPB  392                // points per block
#define BLK  256
#define NB   (BT * BPS)         // 128 blocks
#define SLOTS 64                // per-step slots = BPS * 4 waves

__device__ __forceinline__ unsigned long long key_of(float v, int j) {
  unsigned int u = __float_as_uint(v);
  u = (u & 0x80000000u) ? ~u : (u | 0x80000000u);   // monotone float->uint
  return ((unsigned long long)u << 32) | (unsigned int)(NPTS - j); // low!=0
}
__device__ __forceinline__ unsigned long long kmax(unsigned long long a,
                                                   unsigned long long b) {
  return a > b ? a : b;
}

__global__ __launch_bounds__(BLK, 1) void fps_kernel(const float* __restrict__ x,
                                                     const int* __restrict__ init_,
                                                     int* __restrict__ out_idx,
                                                     unsigned long long* __restrict__ slots) {
  __shared__ float2 xls[NPAIR][PPB];   // own coords, channel-pair-major

  const int bid  = (int)blockIdx.x;
  const int b    = bid / BPS;          // segment 0..7
  const int sub  = bid % BPS;          // sub-block within segment
  const int tid  = (int)threadIdx.x;
  const int lane = tid & 63;
  const int wid  = tid >> 6;
  const int j0   = sub * PPB;
  const float* xg = x + (size_t)b * NPTS * CDIM;
  unsigned long long* seg = slots + (size_t)b * KSEL * SLOTS;

  float sqr[2], df[2];

  // ---- one-time stage: coords -> LDS pairs, sq (strict sequential) ----
#pragma unroll
  for (int p = 0; p < 2; ++p) {
    const int lp = p * BLK + tid;
    if (lp < PPB) {
      const float* src = xg + (size_t)(j0 + lp) * CDIM;
      float v[CDIM];
      float acc = 0.0f;
      {
#pragma clang fp contract(off)
#pragma unroll
        for (int c = 0; c < CDIM; ++c) { v[c] = src[c]; acc = acc + v[c] * v[c]; }
      }
      sqr[p] = acc;
      df[p] = 50000.0f;                // FILL_DIST
#pragma unroll
      for (int ci = 0; ci < NPAIR; ++ci) {
        float2 w;
        w.x = v[2 * ci];
        w.y = (2 * ci + 1 < CDIM) ? v[2 * ci + 1] : 0.0f;  // pad channel = 0
        xls[ci][lp] = w;
      }
    }
  }

  int far;
  { int f = init_[b] % NPTS; if (f < 0) f += NPTS; far = f; }  // jnp.remainder
  if (sub == 0 && tid == 0) out_idx[b * KSEL] = far;

  // ---- 127 sequential FPS steps, zero barriers ----
  for (int step = 1; step < KSEL; ++step) {
    // farthest point's coords: uniform scalar loads (L2-hit broadcast)
    const int fu = __builtin_amdgcn_readfirstlane(far);
    const float* fx = xg + (size_t)fu * CDIM;
    float xf[CDIM + 1];
#pragma unroll
    for (int c = 0; c < CDIM; ++c) xf[c] = fx[c];
    xf[CDIM] = 0.0f;                   // pad channel

    // sqf: sequential chain from identical f32 values -> bitwise equal.
    // Depth matches the dot chain and both depend only on xf, so this is
    // off the critical path (overlaps dot issue).
    float sqf;
    {
#pragma clang fp contract(off)
      float a = 0.0f;
#pragma unroll
      for (int c = 0; c < CDIM; ++c) { float t = xf[c]; a = a + t * t; }
      sqf = a;
    }

    unsigned long long bk = 0ull;
#pragma unroll
    for (int p = 0; p < 2; ++p) {
      const int lp = p * BLK + tid;
      if (lp < PPB) {
        float dot = 0.0f;
#pragma unroll
        for (int ci = 0; ci < NPAIR; ++ci) {
          float2 v = xls[ci][lp];                         // ds_read_b64
          dot = __builtin_fmaf(xf[2 * ci], v.x, dot);     // k-sequential FMA
          dot = __builtin_fmaf(xf[2 * ci + 1], v.y, dot); // pad: fma(0,0,d)=d
        }
        float d2;
        {
#pragma clang fp contract(off)
          d2 = (sqf + sqr[p]) - 2.0f * dot;               // reference order
        }
        d2 = fmaxf(d2, 0.0f);
        float d = __fsqrt_rn(d2);
        const int j = j0 + lp;
        d = (j == far) ? -1.0f : d;                       // diagonal = -1
        float nd = fminf(d, df[p]);                       // f32 min-carry
        df[p] = nd;
        bk = kmax(bk, key_of(nd, j));
      }
    }

    // wave butterfly max — every lane gets the wave's best key
#pragma unroll
    for (int m = 1; m < 64; m <<= 1)
      bk = kmax(bk, __shfl_xor(bk, m));

    // per-wave publish (payload self-contained -> RELAXED, no fence)
    if (lane == 0)
      __hip_atomic_store(&seg[step * SLOTS + sub * 4 + wid], bk,
                         __ATOMIC_RELAXED, __HIP_MEMORY_SCOPE_AGENT);
    asm volatile("" ::: "memory");     // keep store ahead of the spin loop

    // 64 lanes poll the 64 per-step slots (one coalesced 512B line group)
    unsigned long long k = 0ull;
    const unsigned long long* sp = &seg[step * SLOTS + lane];
    do {
      if (k == 0ull)
        k = __hip_atomic_load(sp, __ATOMIC_RELAXED, __HIP_MEMORY_SCOPE_AGENT);
    } while (__any(k == 0ull));

    // butterfly max over the 64 polled keys — winner in every lane
#pragma unroll
    for (int m = 1; m < 64; m <<= 1)
      k = kmax(k, __shfl_xor(k, m));

    far = NPTS - (int)(unsigned int)(k & 0xFFFFFFFFull);
    if (sub == 0 && tid == 0) out_idx[b * KSEL + step] = far;
  }
}

// ---------------------------------------------------------------------------
// gather patches (first 32 channels) + write indices (as f32)
// ---------------------------------------------------------------------------
__global__ __launch_bounds__(256) void gather_kernel(const float* __restrict__ x,
                                                     const int* __restrict__ out_idx,
                                                     float* __restrict__ patches,
                                                     float* __restrict__ sidx) {
  const int b = (int)blockIdx.x;     // 0..3
  const int m = (int)threadIdx.x;    // 0..255
  const int td = m >> 7;             // time segment 0/1
  const int i  = m & 127;
  const int li = out_idx[(b * 2 + td) * KSEL + i];
  const int gi = li + td * NPTS;
  sidx[b * 256 + m] = (float)gi;
  const float* src = x + ((size_t)b * THW + gi) * CDIM;
  float* dst = patches + ((size_t)b * 256 + m) * 32;
#pragma unroll
  for (int c = 0; c < 32; ++c) dst[c] = src[c];   // first C-3 channels
}

extern "C" void kernel_launch(void* const* d_in, const int* in_sizes, int n_in,
                              void* d_out, int out_size, void* d_ws, size_t ws_size,
                              hipStream_t stream) {
  const float* x    = (const float*)d_in[0];
  const int*   init = (const int*)d_in[1];
  (void)in_sizes; (void)n_in; (void)out_size; (void)ws_size;

  unsigned long long* slots = (unsigned long long*)d_ws;
  const size_t slots_bytes = (size_t)BT * KSEL * SLOTS * sizeof(unsigned long long);
  int* idx = (int*)((char*)d_ws + slots_bytes);

  float* patches = (float*)d_out;
  float* sidx    = patches + (size_t)4 * 256 * 32;

  hipMemsetAsync(d_ws, 0, slots_bytes, stream);   // zero sync slots per launch

  void* kargs[] = { (void*)&x, (void*)&init, (void*)&idx, (void*)&slots };
  hipLaunchCooperativeKernel((const void*)fps_kernel, dim3(NB), dim3(BLK),
                             kargs, 0, stream);

  hipLaunchKernelGGL(gather_kernel, dim3(4), dim3(256), 0, stream,
                     x, idx, patches, sidx);
}

// Round 8
// 269.157 us; speedup vs baseline: 1.7914x; 1.7914x over previous
//
#include <hip/hip_runtime.h>

// KCenterSampler FPS — round-4 proven structure + laundered register-resident
// coordinates. 8 segments × 16 blocks (128 blocks, cooperative). Each
// 256-thread block owns 392 points; coords/sq/dist live in VGPRs — each
// loaded value is passed through an empty asm so the compiler CANNOT
// re-materialize the global loads inside the step loop (round-4 bug:
// VGPR_Count=56 showed full re-load every step).
// Sync leg is byte-identical to round 4 (agent-scope RELAXED u64 slots,
// self-contained payload, 2 barriers/step) — known correct, no deadlock.
// Arithmetic bit-identical to the verified round-1/3/4 kernels (absmax 0).

#define NPTS 6272
#define CDIM 35
#define BT   8
#define KSEL 128
#define THW  12544
#define BPS  16                  // blocks per segment
#define PPB  392                 // points per block
#define BLK  256
#define NB   (BT * BPS)          // 128 blocks
#define TAILN (PPB - BLK)        // 136: threads owning a 2nd point

__device__ __forceinline__ unsigned long long key_of(float v, int j) {
  unsigned int u = __float_as_uint(v);
  u = (u & 0x80000000u) ? ~u : (u | 0x80000000u);   // monotone float->uint
  return ((unsigned long long)u << 32) | (unsigned int)(NPTS - j); // low!=0
}
__device__ __forceinline__ unsigned long long kmax(unsigned long long a,
                                                   unsigned long long b) {
  return a > b ? a : b;
}

__global__ __launch_bounds__(BLK, 1) void fps_kernel(const float* __restrict__ x,
                                                     const int* __restrict__ init_,
                                                     int* __restrict__ out_idx,
                                                     unsigned long long* __restrict__ slots) {
  __shared__ unsigned long long wk[4];
  __shared__ int far_s;

  const int bid  = (int)blockIdx.x;
  const int b    = bid / BPS;          // segment 0..7
  const int sub  = bid % BPS;          // sub-block within segment
  const int tid  = (int)threadIdx.x;
  const int lane = tid & 63;
  const int wid  = tid >> 6;
  const int j0   = sub * PPB;
  const float* xg = x + (size_t)b * NPTS * CDIM;
  unsigned long long* seg = slots + (size_t)b * KSEL * BPS;

  // ---- one-time load: coords -> VGPRs (laundered), sq sequential ----
  float xr0[CDIM], xr1[CDIM];
  float sqr0, sqr1, df0, df1;
  {
    const float* src0 = xg + (size_t)(j0 + tid) * CDIM;
    float acc = 0.0f;
    {
#pragma clang fp contract(off)
#pragma unroll
      for (int c = 0; c < CDIM; ++c) { float v = src0[c]; xr0[c] = v; acc = acc + v * v; }
    }
    sqr0 = acc; df0 = 50000.0f;
    sqr1 = 0.0f; df1 = 50000.0f;
#pragma unroll
    for (int c = 0; c < CDIM; ++c) xr1[c] = 0.0f;
    if (tid < TAILN) {
      const float* src1 = xg + (size_t)(j0 + BLK + tid) * CDIM;
      float acc1 = 0.0f;
      {
#pragma clang fp contract(off)
#pragma unroll
        for (int c = 0; c < CDIM; ++c) { float v = src1[c]; xr1[c] = v; acc1 = acc1 + v * v; }
      }
      sqr1 = acc1;
    }
    // launder: opaque defs — compiler cannot re-materialize from memory
#pragma unroll
    for (int c = 0; c < CDIM; ++c) {
      asm volatile("" : "+v"(xr0[c]));
      asm volatile("" : "+v"(xr1[c]));
    }
    asm volatile("" : "+v"(sqr0));
    asm volatile("" : "+v"(sqr1));
  }

  int far;
  { int f = init_[b] % NPTS; if (f < 0) f += NPTS; far = f; }  // jnp.remainder
  if (sub == 0 && tid == 0) out_idx[b * KSEL] = far;

  // ---- 127 sequential FPS steps ----
  for (int step = 1; step < KSEL; ++step) {
    // farthest point's coords: uniform-address broadcast loads (L2-hit)
    const int fu = __builtin_amdgcn_readfirstlane(far);
    const float* fx = xg + (size_t)fu * CDIM;
    float xf[CDIM];
#pragma unroll
    for (int c = 0; c < CDIM; ++c) xf[c] = fx[c];

    // sqf: sequential chain from identical f32 values -> bitwise equal;
    // depends only on xf, overlaps the dot chains.
    float sqf;
    {
#pragma clang fp contract(off)
      float a = 0.0f;
#pragma unroll
      for (int c = 0; c < CDIM; ++c) { float t = xf[c]; a = a + t * t; }
      sqf = a;
    }

    // point 0 (all threads)
    unsigned long long bk;
    {
      float dot = 0.0f;
#pragma unroll
      for (int c = 0; c < CDIM; ++c)
        dot = __builtin_fmaf(xf[c], xr0[c], dot);          // k-sequential FMA
      float d2;
      {
#pragma clang fp contract(off)
        d2 = (sqf + sqr0) - 2.0f * dot;                    // reference order
      }
      d2 = fmaxf(d2, 0.0f);
      float d = __fsqrt_rn(d2);
      const int j = j0 + tid;
      d = (j == far) ? -1.0f : d;                          // diagonal = -1
      float nd = fminf(d, df0);                            // f32 min-carry
      df0 = nd;
      bk = key_of(nd, j);
    }
    // point 1 (threads 0..135)
    if (tid < TAILN) {
      float dot = 0.0f;
#pragma unroll
      for (int c = 0; c < CDIM; ++c)
        dot = __builtin_fmaf(xf[c], xr1[c], dot);
      float d2;
      {
#pragma clang fp contract(off)
        d2 = (sqf + sqr1) - 2.0f * dot;
      }
      d2 = fmaxf(d2, 0.0f);
      float d = __fsqrt_rn(d2);
      const int j = j0 + BLK + tid;
      d = (j == far) ? -1.0f : d;
      float nd = fminf(d, df1);
      df1 = nd;
      bk = kmax(bk, key_of(nd, j));
    }

    // wave-level max of packed keys (order = (value, first-index))
#pragma unroll
    for (int off = 32; off > 0; off >>= 1)
      bk = kmax(bk, __shfl_down(bk, off));
    if (lane == 0) wk[wid] = bk;
    __syncthreads();                                       // barrier 1

    if (tid < BPS) {
      if (tid == 0) {
        unsigned long long m = kmax(kmax(wk[0], wk[1]), kmax(wk[2], wk[3]));
        // payload self-contained -> RELAXED agent scope, no fence
        __hip_atomic_store(&seg[step * BPS + sub], m,
                           __ATOMIC_RELAXED, __HIP_MEMORY_SCOPE_AGENT);
      }
      asm volatile("" ::: "memory");   // keep store ahead of the spin loop
      unsigned long long k;
      do {
        k = __hip_atomic_load(&seg[step * BPS + tid],
                              __ATOMIC_RELAXED, __HIP_MEMORY_SCOPE_AGENT);
      } while (k == 0ull);
      // in-wave max over the 16 polled keys (lanes 0..15)
#pragma unroll
      for (int off = 8; off > 0; off >>= 1)
        k = kmax(k, __shfl_down(k, off));
      if (tid == 0) {
        int f = NPTS - (int)(unsigned int)(k & 0xFFFFFFFFull);
        far_s = f;
        if (sub == 0) out_idx[b * KSEL + step] = f;
      }
    }
    __syncthreads();                                       // barrier 2
    far = far_s;
  }
}

// ---------------------------------------------------------------------------
// gather patches (first 32 channels) + write indices (as f32)
// ---------------------------------------------------------------------------
__global__ __launch_bounds__(256) void gather_kernel(const float* __restrict__ x,
                                                     const int* __restrict__ out_idx,
                                                     float* __restrict__ patches,
                                                     float* __restrict__ sidx) {
  const int b = (int)blockIdx.x;     // 0..3
  const int m = (int)threadIdx.x;    // 0..255
  const int td = m >> 7;             // time segment 0/1
  const int i  = m & 127;
  const int li = out_idx[(b * 2 + td) * KSEL + i];
  const int gi = li + td * NPTS;
  sidx[b * 256 + m] = (float)gi;
  const float* src = x + ((size_t)b * THW + gi) * CDIM;
  float* dst = patches + ((size_t)b * 256 + m) * 32;
#pragma unroll
  for (int c = 0; c < 32; ++c) dst[c] = src[c];   // first C-3 channels
}

extern "C" void kernel_launch(void* const* d_in, const int* in_sizes, int n_in,
                              void* d_out, int out_size, void* d_ws, size_t ws_size,
                              hipStream_t stream) {
  const float* x    = (const float*)d_in[0];
  const int*   init = (const int*)d_in[1];
  (void)in_sizes; (void)n_in; (void)out_size; (void)ws_size;

  // ws layout: slots [BT*KSEL*BPS u64] | idx [BT*KSEL int]
  unsigned long long* slots = (unsigned long long*)d_ws;
  const size_t slots_bytes = (size_t)BT * KSEL * BPS * sizeof(unsigned long long);
  int* idx = (int*)((char*)d_ws + slots_bytes);

  float* patches = (float*)d_out;
  float* sidx    = patches + (size_t)4 * 256 * 32;

  hipMemsetAsync(d_ws, 0, slots_bytes, stream);   // zero sync slots per launch

  void* kargs[] = { (void*)&x, (void*)&init, (void*)&idx, (void*)&slots };
  hipLaunchCooperativeKernel((const void*)fps_kernel, dim3(NB), dim3(BLK),
                             kargs, 0, stream);

  hipLaunchKernelGGL(gather_kernel, dim3(4), dim3(256), 0, stream,
                     x, idx, patches, sidx);
}